// Round 3
// baseline (1091.264 us; speedup 1.0000x reference)
//
#include <hip/hip_runtime.h>
#include <stdint.h>
#include <stddef.h>

#define N_NODES 200000
#define N_EDGES 800000
#define NREL 16
#define NBASES 8
#define BSZ 128                          // nodes per target bucket
#define NB  ((N_NODES + BSZ - 1) / BSZ)  // 1563 buckets
#define NKEY (NB * NREL)                 // 25008 (bucket, rel) keys
#define MAXREC 2000000                   // >= 1.6M msgs + 25008*15 pad

// ---- workspace layout (bytes) ----
#define WS_CNT    0                      // NKEY int      (100,032) -> pad 100352
#define WS_START  100352                 // NKEY int                -> pad 200704
#define WS_CUR    200704                 // NKEY int                -> pad 301056
#define WS_WT     301056                 // 17*64*64 u16 (139,264)  -> 440320
#define WS_XB     440320                 // (N_NODES+1)*64 u16 (25,600,128)
#define WS_REC    26040448               // MAXREC u32 (8,000,000)
#define WS_TOTAL  (WS_REC + (size_t)MAXREC * 4)

typedef __attribute__((ext_vector_type(8))) short short8b;
typedef __attribute__((ext_vector_type(4))) float float4v;

__device__ __forceinline__ short f32_bf16(float f) {
  uint32_t u = __builtin_bit_cast(uint32_t, f);
  uint32_t r = u + 0x7FFFu + ((u >> 16) & 1u);
  return (short)(uint16_t)(r >> 16);
}

// Wt[r][e][d] = bf16( sum_b att[r][b] * bases[b][d][e] )  (row e = out-dim, col d = k)
__global__ __launch_bounds__(256) void k_wprep(const float* __restrict__ bases,
                                               const float* __restrict__ att,
                                               uint16_t* __restrict__ Wt) {
  int i = blockIdx.x * 256 + threadIdx.x;
  if (i >= 17 * 64 * 64) return;
  int r = i >> 12;
  int e = (i >> 6) & 63;
  int d = i & 63;
  float acc = 0.f;
  for (int b = 0; b < NBASES; ++b)
    acc += att[r * NBASES + b] * bases[b * 4096 + d * 64 + e];
  Wt[i] = (uint16_t)f32_bf16(acc);
}

// x -> bf16, plus a zeroed sentinel row at index N_NODES
__global__ __launch_bounds__(256) void k_xprep(const float* __restrict__ x,
                                               uint16_t* __restrict__ xb) {
  int i4 = blockIdx.x * 256 + threadIdx.x;          // float4 index
  if (i4 >= (N_NODES + 1) * 16) return;
  int n = i4 >> 4;
  ushort4 o;
  if (n < N_NODES) {
    float4 f = ((const float4*)x)[i4];
    o.x = (uint16_t)f32_bf16(f.x);
    o.y = (uint16_t)f32_bf16(f.y);
    o.z = (uint16_t)f32_bf16(f.z);
    o.w = (uint16_t)f32_bf16(f.w);
  } else {
    o.x = 0; o.y = 0; o.z = 0; o.w = 0;
  }
  ((ushort4*)xb)[i4] = o;
}

__global__ __launch_bounds__(256) void k_cnt(const int* __restrict__ src,
                                             const int* __restrict__ tgt,
                                             const int* __restrict__ et,
                                             int* __restrict__ cnt, int nE) {
  int i = blockIdx.x * 256 + threadIdx.x;
  if (i >= nE) return;
  int s = src[i], t = tgt[i], r = et[i];
  atomicAdd(&cnt[(t >> 7) * NREL + r], 1);   // msg s->t lands in t's bucket
  atomicAdd(&cnt[(s >> 7) * NREL + r], 1);   // msg t->s lands in s's bucket
}

// exclusive scan of 16-aligned slot sizes over NKEY keys (one block)
__global__ __launch_bounds__(256) void k_prefix(const int* __restrict__ cnt,
                                                int* __restrict__ start,
                                                int* __restrict__ cur) {
  __shared__ int ps[256];
  const int CH = (NKEY + 255) / 256;   // 98
  int t = threadIdx.x;
  int lo = t * CH;
  int hi = lo + CH; if (hi > NKEY) hi = NKEY;
  int s = 0;
  for (int i = lo; i < hi; ++i) s += (cnt[i] + 15) & ~15;
  ps[t] = s;
  __syncthreads();
  int incl = s;
  for (int off = 1; off < 256; off <<= 1) {
    int a = (t >= off) ? ps[t - off] : 0;
    __syncthreads();
    incl += a;
    ps[t] = incl;
    __syncthreads();
  }
  int run = incl - s;
  for (int i = lo; i < hi; ++i) {
    start[i] = run;
    cur[i] = run;
    run += (cnt[i] + 15) & ~15;
  }
}

// rec = (tloc<<24) | gather_node ; padded slots stay 0xFFFFFFFF (memset)
__global__ __launch_bounds__(256) void k_scat(const int* __restrict__ src,
                                              const int* __restrict__ tgt,
                                              const int* __restrict__ et,
                                              uint32_t* __restrict__ rec,
                                              int* __restrict__ cur, int nE) {
  int i = blockIdx.x * 256 + threadIdx.x;
  if (i >= nE) return;
  int s = src[i], t = tgt[i], r = et[i];
  int p1 = atomicAdd(&cur[(t >> 7) * NREL + r], 1);
  rec[p1] = ((uint32_t)(t & 127) << 24) | (uint32_t)s;
  int p2 = atomicAdd(&cur[(s >> 7) * NREL + r], 1);
  rec[p2] = ((uint32_t)(s & 127) << 24) | (uint32_t)t;
}

// one block per 128-node bucket; LDS fp32 accumulator; MFMA per relation group
__global__ __launch_bounds__(256, 4) void k_fused(const uint16_t* __restrict__ xb,
                                                  const uint32_t* __restrict__ recbuf,
                                                  const uint16_t* __restrict__ Wt,
                                                  const int* __restrict__ cnt,
                                                  const int* __restrict__ start,
                                                  const int* __restrict__ mask,
                                                  float* __restrict__ out) {
  __shared__ float lacc[BSZ * 68];       // stride 68: 16B-aligned rows, bank stagger
  const int b = blockIdx.x;
  const int base = b * BSZ;
  const int wid = threadIdx.x >> 6;
  const int lane = threadIdx.x & 63;
  const int quad = lane >> 4;
  const int m16 = lane & 15;

  for (int i = threadIdx.x; i < BSZ * 68; i += 256) lacc[i] = 0.f;
  __syncthreads();

  // ---- edge tiles: this wave owns relations wid, wid+4, wid+8, wid+12 ----
  for (int rr = 0; rr < 4; ++rr) {
    int r = wid + rr * 4;
    int key = b * NREL + r;
    int c = cnt[key];
    if (c == 0) continue;
    int ntile = (c + 15) >> 4;
    int sbase = start[key];
    const uint16_t* wb = Wt + (size_t)r * 4096;
    short8b bf[4][2];
    for (int nt = 0; nt < 4; ++nt)
      for (int kt = 0; kt < 2; ++kt)
        bf[nt][kt] = *(const short8b*)(wb + (size_t)(nt * 16 + m16) * 64 + kt * 32 + quad * 8);

    for (int it = 0; it < ntile; ++it) {
      uint32_t rec = recbuf[sbase + it * 16 + m16];
      uint32_t u = rec & 0xFFFFFFu;
      if (u > N_NODES) u = N_NODES;              // sentinel -> zero row
      int tloc = (rec >> 24) & (BSZ - 1);        // sentinel adds 0.0 somewhere: harmless

      const uint16_t* xp = xb + (size_t)u * 64 + quad * 8;
      short8b a0 = *(const short8b*)(xp);
      short8b a1 = *(const short8b*)(xp + 32);

      float4v acc[4];
      for (int nt = 0; nt < 4; ++nt) { acc[nt][0] = 0.f; acc[nt][1] = 0.f; acc[nt][2] = 0.f; acc[nt][3] = 0.f; }
      for (int nt = 0; nt < 4; ++nt) {
        acc[nt] = __builtin_amdgcn_mfma_f32_16x16x32_bf16(a0, bf[nt][0], acc[nt], 0, 0, 0);
        acc[nt] = __builtin_amdgcn_mfma_f32_16x16x32_bf16(a1, bf[nt][1], acc[nt], 0, 0, 0);
      }
      // C/D: col(dim)=nt*16+m16, row(msg)=quad*4+reg; fetch row's tloc via shuffle
      int tl[4];
      for (int reg = 0; reg < 4; ++reg) tl[reg] = __shfl(tloc, quad * 4 + reg, 64);
      for (int reg = 0; reg < 4; ++reg)
        for (int nt = 0; nt < 4; ++nt)
          atomicAdd(&lacc[tl[reg] * 68 + nt * 16 + m16], acc[nt][reg]);
    }
  }

  // ---- self tiles (rel 16): wave handles node sub-tiles wid*2, wid*2+1 ----
  {
    const uint16_t* wb = Wt + (size_t)NREL * 4096;
    short8b bf[4][2];
    for (int nt = 0; nt < 4; ++nt)
      for (int kt = 0; kt < 2; ++kt)
        bf[nt][kt] = *(const short8b*)(wb + (size_t)(nt * 16 + m16) * 64 + kt * 32 + quad * 8);
    for (int j = 0; j < 2; ++j) {
      int s16 = wid * 2 + j;
      int node = base + s16 * 16 + m16;
      uint32_t u = (node < N_NODES && mask[node]) ? (uint32_t)node : (uint32_t)N_NODES;
      const uint16_t* xp = xb + (size_t)u * 64 + quad * 8;
      short8b a0 = *(const short8b*)(xp);
      short8b a1 = *(const short8b*)(xp + 32);
      float4v acc[4];
      for (int nt = 0; nt < 4; ++nt) { acc[nt][0] = 0.f; acc[nt][1] = 0.f; acc[nt][2] = 0.f; acc[nt][3] = 0.f; }
      for (int nt = 0; nt < 4; ++nt) {
        acc[nt] = __builtin_amdgcn_mfma_f32_16x16x32_bf16(a0, bf[nt][0], acc[nt], 0, 0, 0);
        acc[nt] = __builtin_amdgcn_mfma_f32_16x16x32_bf16(a1, bf[nt][1], acc[nt], 0, 0, 0);
      }
      for (int reg = 0; reg < 4; ++reg)
        for (int nt = 0; nt < 4; ++nt)
          atomicAdd(&lacc[(s16 * 16 + quad * 4 + reg) * 68 + nt * 16 + m16], acc[nt][reg]);
    }
  }

  __syncthreads();
  // ---- writeout: 128 rows x 64 dims, float4 per thread, coalesced ----
  for (int p = 0; p < 8; ++p) {
    int tloc = p * 16 + (threadIdx.x >> 4);
    int node = base + tloc;
    if (node < N_NODES) {
      int d = (threadIdx.x & 15) * 4;
      float4 v = *(const float4*)&lacc[tloc * 68 + d];
      *(float4*)(out + (size_t)node * 64 + d) = v;
    }
  }
}

extern "C" void kernel_launch(void* const* d_in, const int* in_sizes, int n_in,
                              void* d_out, int out_size, void* d_ws, size_t ws_size,
                              hipStream_t stream) {
  const float* x     = (const float*)d_in[0];
  const int*   mask  = (const int*)d_in[1];
  const int*   src   = (const int*)d_in[2];
  const int*   tgt   = (const int*)d_in[3];
  const int*   et    = (const int*)d_in[4];
  const float* bases = (const float*)d_in[5];
  const float* att   = (const float*)d_in[6];
  float* out = (float*)d_out;
  char* ws = (char*)d_ws;

  int*      cnt    = (int*)(ws + WS_CNT);
  int*      start  = (int*)(ws + WS_START);
  int*      cur    = (int*)(ws + WS_CUR);
  uint16_t* Wt     = (uint16_t*)(ws + WS_WT);
  uint16_t* xb     = (uint16_t*)(ws + WS_XB);
  uint32_t* recbuf = (uint32_t*)(ws + WS_REC);

  hipMemsetAsync(cnt, 0, NKEY * sizeof(int), stream);
  hipMemsetAsync(recbuf, 0xFF, (size_t)MAXREC * 4, stream);

  k_wprep<<<(17 * 64 * 64 + 255) / 256, 256, 0, stream>>>(bases, att, Wt);
  k_xprep<<<((N_NODES + 1) * 16 + 255) / 256, 256, 0, stream>>>(x, xb);
  k_cnt<<<(N_EDGES + 255) / 256, 256, 0, stream>>>(src, tgt, et, cnt, N_EDGES);
  k_prefix<<<1, 256, 0, stream>>>(cnt, start, cur);
  k_scat<<<(N_EDGES + 255) / 256, 256, 0, stream>>>(src, tgt, et, recbuf, cur, N_EDGES);
  k_fused<<<NB, 256, 0, stream>>>(xb, recbuf, Wt, cnt, start, mask, out);
}

// Round 4
// 1084.781 us; speedup vs baseline: 1.0060x; 1.0060x over previous
//
#include <hip/hip_runtime.h>
#include <stdint.h>
#include <stddef.h>

#define N_NODES 200000
#define N_EDGES 800000
#define NREL 16
#define NBASES 8
#define BSZ 128                          // nodes per target bucket
#define NB  ((N_NODES + BSZ - 1) / BSZ)  // 1563 buckets
#define NKEY (NB * NREL)                 // 25008 (bucket, rel) keys
#define MAXREC 2000000                   // 1.6M msgs + <=375K pad

// record encoding: node [0:18) | rel [18:23) | tloc [23:30); sentinel = 0xFFFFFFFF
// ---- workspace layout (bytes) ----
#define WS_CNT    0
#define WS_START  102400
#define WS_CUR    204800
#define WS_WT     307200                 // 17*64*64 u16 (139,264)
#define WS_XB     446464                 // (N_NODES+1)*64 u16 (25,600,128)
#define WS_REC    26046592               // MAXREC u32

typedef __attribute__((ext_vector_type(8))) short short8b;
typedef __attribute__((ext_vector_type(4))) float float4v;

__device__ __forceinline__ short f32_bf16(float f) {
  uint32_t u = __builtin_bit_cast(uint32_t, f);
  uint32_t r = u + 0x7FFFu + ((u >> 16) & 1u);
  return (short)(uint16_t)(r >> 16);
}

// fused prep: W table (blocks [0,272)), x->bf16 (blocks [272,12773)), rel/bucket count (rest)
#define PREP_W   272
#define PREP_X   12501
#define PREP_C   3125
__global__ __launch_bounds__(256) void k_prep(const float* __restrict__ bases,
                                              const float* __restrict__ att,
                                              const float* __restrict__ x,
                                              const int* __restrict__ src,
                                              const int* __restrict__ tgt,
                                              const int* __restrict__ et,
                                              uint16_t* __restrict__ Wt,
                                              uint16_t* __restrict__ xb,
                                              int* __restrict__ cnt) {
  int bid = blockIdx.x;
  if (bid < PREP_W) {
    // Wt[r][e][d] = bf16( sum_b att[r][b] * bases[b][d][e] )
    int i = bid * 256 + threadIdx.x;     // < 69632 exactly
    int r = i >> 12, e = (i >> 6) & 63, d = i & 63;
    float acc = 0.f;
    for (int b = 0; b < NBASES; ++b)
      acc += att[r * NBASES + b] * bases[b * 4096 + d * 64 + e];
    Wt[i] = (uint16_t)f32_bf16(acc);
  } else if (bid < PREP_W + PREP_X) {
    int i4 = (bid - PREP_W) * 256 + threadIdx.x;
    if (i4 >= (N_NODES + 1) * 16) return;
    ushort4 o;
    if (i4 < N_NODES * 16) {
      float4 f = ((const float4*)x)[i4];
      o.x = (uint16_t)f32_bf16(f.x);
      o.y = (uint16_t)f32_bf16(f.y);
      o.z = (uint16_t)f32_bf16(f.z);
      o.w = (uint16_t)f32_bf16(f.w);
    } else {
      o.x = 0; o.y = 0; o.z = 0; o.w = 0;
    }
    ((ushort4*)xb)[i4] = o;
  } else {
    int i = (bid - PREP_W - PREP_X) * 256 + threadIdx.x;
    if (i >= N_EDGES) return;
    int s = src[i], t = tgt[i], r = et[i];
    atomicAdd(&cnt[(t >> 7) * NREL + r], 1);
    atomicAdd(&cnt[(s >> 7) * NREL + r], 1);
  }
}

// exclusive scan of 16-aligned slot sizes; start[NKEY] = total
__global__ __launch_bounds__(256) void k_prefix(const int* __restrict__ cnt,
                                                int* __restrict__ start,
                                                int* __restrict__ cur) {
  __shared__ int ps[256];
  const int CH = (NKEY + 255) / 256;     // 98
  int t = threadIdx.x;
  int lo = t * CH;
  int hi = lo + CH; if (hi > NKEY) hi = NKEY;
  int s = 0;
  for (int i = lo; i < hi; ++i) s += (cnt[i] + 15) & ~15;
  ps[t] = s;
  __syncthreads();
  int incl = s;
  for (int off = 1; off < 256; off <<= 1) {
    int a = (t >= off) ? ps[t - off] : 0;
    __syncthreads();
    incl += a;
    ps[t] = incl;
    __syncthreads();
  }
  int run = incl - s;
  for (int i = lo; i < hi; ++i) {
    start[i] = run;
    cur[i] = run;
    run += (cnt[i] + 15) & ~15;
  }
  if (t == 255) start[NKEY] = run;
}

__global__ __launch_bounds__(256) void k_scat(const int* __restrict__ src,
                                              const int* __restrict__ tgt,
                                              const int* __restrict__ et,
                                              uint32_t* __restrict__ rec,
                                              int* __restrict__ cur, int nE) {
  int i = blockIdx.x * 256 + threadIdx.x;
  if (i >= nE) return;
  int s = src[i], t = tgt[i], r = et[i];
  int p1 = atomicAdd(&cur[(t >> 7) * NREL + r], 1);
  rec[p1] = ((uint32_t)(t & 127) << 23) | ((uint32_t)r << 18) | (uint32_t)s;
  int p2 = atomicAdd(&cur[(s >> 7) * NREL + r], 1);
  rec[p2] = ((uint32_t)(s & 127) << 23) | ((uint32_t)r << 18) | (uint32_t)t;
}

// one block per bucket; flattened tile list; 8-tile statically-unrolled batches
__global__ __launch_bounds__(256) void k_fused(const uint16_t* __restrict__ xb,
                                               const uint32_t* __restrict__ recbuf,
                                               const uint16_t* __restrict__ Wt,
                                               const int* __restrict__ start,
                                               const int* __restrict__ mask,
                                               float* __restrict__ out) {
  __shared__ float lacc[BSZ * 68];       // stride 68: 16B-aligned rows, bank stagger
  const int b = blockIdx.x;
  const int base = b * BSZ;
  const int wid = threadIdx.x >> 6;
  const int lane = threadIdx.x & 63;
  const int quad = lane >> 4;
  const int m16 = lane & 15;

  {
    float4* z = (float4*)lacc;
    for (int i = threadIdx.x; i < BSZ * 68 / 4; i += 256)
      z[i] = make_float4(0.f, 0.f, 0.f, 0.f);
  }
  __syncthreads();

  const int bstart = start[b * NREL];
  const int bend = start[(b + 1) * NREL];
  const int ntiles = (bend - bstart) >> 4;

  int curRel = -1;
  short8b bf[4][2] = {};

  for (int t0 = wid * 8; t0 < ntiles; t0 += 32) {
    // ---- load 8 tiles of records: 2 coalesced loads ----
    int i0 = bstart + t0 * 16 + lane;
    int i1 = i0 + 64;
    uint32_t r0 = (i0 < bend) ? recbuf[i0] : 0xFFFFFFFFu;
    uint32_t r1 = (i1 < bend) ? recbuf[i1] : 0xFFFFFFFFu;

    // msg-aligned recs: lane holds msg m16's record for each tile
    uint32_t mrec[8];
#pragma unroll
    for (int it = 0; it < 4; ++it) mrec[it] = __shfl(r0, it * 16 + m16, 64);
#pragma unroll
    for (int it = 0; it < 4; ++it) mrec[4 + it] = __shfl(r1, it * 16 + m16, 64);

    // ---- issue all 16 gathers before any MFMA ----
    short8b a0[8], a1[8];
#pragma unroll
    for (int it = 0; it < 8; ++it) {
      uint32_t u = mrec[it] & 0x3FFFFu;
      if (u > N_NODES) u = N_NODES;      // sentinel -> zero row
      const uint16_t* xp = xb + (size_t)u * 64 + quad * 8;
      a0[it] = *(const short8b*)(xp);
      a1[it] = *(const short8b*)(xp + 32);
    }

    // ---- compute + LDS scatter per tile ----
#pragma unroll
    for (int it = 0; it < 8; ++it) {
      uint32_t tilerec = (it < 4) ? __shfl(r0, (it & 3) * 16, 64)
                                  : __shfl(r1, (it & 3) * 16, 64);
      int rel = (int)((tilerec >> 18) & 31);
      if (rel == 31) continue;           // tile fully past bucket end (uniform)
      if (rel != curRel) {
        curRel = rel;
        const uint16_t* wb = Wt + (size_t)rel * 4096;
#pragma unroll
        for (int nt = 0; nt < 4; ++nt)
#pragma unroll
          for (int kt = 0; kt < 2; ++kt)
            bf[nt][kt] = *(const short8b*)(wb + (size_t)(nt * 16 + m16) * 64 + kt * 32 + quad * 8);
      }
      float4v acc[4];
#pragma unroll
      for (int nt = 0; nt < 4; ++nt) { acc[nt][0] = 0.f; acc[nt][1] = 0.f; acc[nt][2] = 0.f; acc[nt][3] = 0.f; }
#pragma unroll
      for (int nt = 0; nt < 4; ++nt) {
        acc[nt] = __builtin_amdgcn_mfma_f32_16x16x32_bf16(a0[it], bf[nt][0], acc[nt], 0, 0, 0);
        acc[nt] = __builtin_amdgcn_mfma_f32_16x16x32_bf16(a1[it], bf[nt][1], acc[nt], 0, 0, 0);
      }
      // C/D: col = nt*16 + m16, row(msg) = quad*4 + reg
      int tl[4];
#pragma unroll
      for (int reg = 0; reg < 4; ++reg)
        tl[reg] = (int)((__shfl(mrec[it], quad * 4 + reg, 64) >> 23) & 127);
#pragma unroll
      for (int reg = 0; reg < 4; ++reg)
#pragma unroll
        for (int nt = 0; nt < 4; ++nt)
          atomicAdd(&lacc[tl[reg] * 68 + nt * 16 + m16], acc[nt][reg]);
    }
  }

  // ---- self tiles (rel 16): wave wid handles node sub-tiles wid*2, wid*2+1 ----
  {
    const uint16_t* wb = Wt + (size_t)NREL * 4096;
    short8b bfs[4][2];
#pragma unroll
    for (int nt = 0; nt < 4; ++nt)
#pragma unroll
      for (int kt = 0; kt < 2; ++kt)
        bfs[nt][kt] = *(const short8b*)(wb + (size_t)(nt * 16 + m16) * 64 + kt * 32 + quad * 8);
#pragma unroll
    for (int j = 0; j < 2; ++j) {
      int s16 = wid * 2 + j;
      int node = base + s16 * 16 + m16;
      uint32_t u = (node < N_NODES && mask[node]) ? (uint32_t)node : (uint32_t)N_NODES;
      const uint16_t* xp = xb + (size_t)u * 64 + quad * 8;
      short8b a0 = *(const short8b*)(xp);
      short8b a1 = *(const short8b*)(xp + 32);
      float4v acc[4];
#pragma unroll
      for (int nt = 0; nt < 4; ++nt) { acc[nt][0] = 0.f; acc[nt][1] = 0.f; acc[nt][2] = 0.f; acc[nt][3] = 0.f; }
#pragma unroll
      for (int nt = 0; nt < 4; ++nt) {
        acc[nt] = __builtin_amdgcn_mfma_f32_16x16x32_bf16(a0, bfs[nt][0], acc[nt], 0, 0, 0);
        acc[nt] = __builtin_amdgcn_mfma_f32_16x16x32_bf16(a1, bfs[nt][1], acc[nt], 0, 0, 0);
      }
#pragma unroll
      for (int reg = 0; reg < 4; ++reg)
#pragma unroll
        for (int nt = 0; nt < 4; ++nt)
          atomicAdd(&lacc[(s16 * 16 + quad * 4 + reg) * 68 + nt * 16 + m16], acc[nt][reg]);
    }
  }

  __syncthreads();
  // ---- writeout: 128 rows x 64 dims, float4/thread, coalesced ----
#pragma unroll
  for (int p = 0; p < 8; ++p) {
    int tloc = p * 16 + (threadIdx.x >> 4);
    int node = base + tloc;
    if (node < N_NODES) {
      int d = (threadIdx.x & 15) * 4;
      float4 v = *(const float4*)&lacc[tloc * 68 + d];
      *(float4*)(out + (size_t)node * 64 + d) = v;
    }
  }
}

extern "C" void kernel_launch(void* const* d_in, const int* in_sizes, int n_in,
                              void* d_out, int out_size, void* d_ws, size_t ws_size,
                              hipStream_t stream) {
  const float* x     = (const float*)d_in[0];
  const int*   mask  = (const int*)d_in[1];
  const int*   src   = (const int*)d_in[2];
  const int*   tgt   = (const int*)d_in[3];
  const int*   et    = (const int*)d_in[4];
  const float* bases = (const float*)d_in[5];
  const float* att   = (const float*)d_in[6];
  float* out = (float*)d_out;
  char* ws = (char*)d_ws;

  int*      cnt    = (int*)(ws + WS_CNT);
  int*      start  = (int*)(ws + WS_START);
  int*      cur    = (int*)(ws + WS_CUR);
  uint16_t* Wt     = (uint16_t*)(ws + WS_WT);
  uint16_t* xb     = (uint16_t*)(ws + WS_XB);
  uint32_t* recbuf = (uint32_t*)(ws + WS_REC);

  hipMemsetAsync(cnt, 0, NKEY * sizeof(int), stream);
  hipMemsetAsync(recbuf, 0xFF, (size_t)MAXREC * 4, stream);

  k_prep<<<PREP_W + PREP_X + PREP_C, 256, 0, stream>>>(bases, att, x, src, tgt, et, Wt, xb, cnt);
  k_prefix<<<1, 256, 0, stream>>>(cnt, start, cur);
  k_scat<<<(N_EDGES + 255) / 256, 256, 0, stream>>>(src, tgt, et, recbuf, cur, N_EDGES);
  k_fused<<<NB, 256, 0, stream>>>(xb, recbuf, Wt, start, mask, out);
}

// Round 5
// 1076.070 us; speedup vs baseline: 1.0141x; 1.0081x over previous
//
#include <hip/hip_runtime.h>
#include <stdint.h>
#include <stddef.h>

#define N_NODES 200000
#define N_EDGES 800000
#define NREL 16
#define NBASES 8
#define BSZ 128                          // nodes per target bucket
#define NB  ((N_NODES + BSZ - 1) / BSZ)  // 1563 buckets
#define NKEY (NB * NREL)                 // 25008 (bucket, rel) keys
#define MAXREC 2000000                   // 1.6M msgs + <=375K pad
#define ACCR (BSZ + 8)                   // 8 dummy rows for pad-message sinks

// record encoding: node [0:18) | rel [18:23) | tloc [23:30); sentinel = 0xFFFFFFFF
// ---- workspace layout (bytes) ----
#define WS_CNT    0
#define WS_START  102400
#define WS_CUR    204800
#define WS_WT     307200                 // 17*64*64 u16 (139,264)
#define WS_XB     446464                 // (N_NODES+1)*64 u16 (25,600,128)
#define WS_REC    26046592               // MAXREC u32

typedef __attribute__((ext_vector_type(8))) short short8b;
typedef __attribute__((ext_vector_type(4))) float float4v;

__device__ __forceinline__ short f32_bf16(float f) {
  uint32_t u = __builtin_bit_cast(uint32_t, f);
  uint32_t r = u + 0x7FFFu + ((u >> 16) & 1u);
  return (short)(uint16_t)(r >> 16);
}

// fused prep: W table (blocks [0,272)), x->bf16 (blocks [272,12773)), rel/bucket count (rest)
#define PREP_W   272
#define PREP_X   12501
#define PREP_C   3125
__global__ __launch_bounds__(256) void k_prep(const float* __restrict__ bases,
                                              const float* __restrict__ att,
                                              const float* __restrict__ x,
                                              const int* __restrict__ src,
                                              const int* __restrict__ tgt,
                                              const int* __restrict__ et,
                                              uint16_t* __restrict__ Wt,
                                              uint16_t* __restrict__ xb,
                                              int* __restrict__ cnt) {
  int bid = blockIdx.x;
  if (bid < PREP_W) {
    // Wt[r][e][d] = bf16( sum_b att[r][b] * bases[b][d][e] )
    int i = bid * 256 + threadIdx.x;     // < 69632 exactly
    int r = i >> 12, e = (i >> 6) & 63, d = i & 63;
    float acc = 0.f;
    for (int b = 0; b < NBASES; ++b)
      acc += att[r * NBASES + b] * bases[b * 4096 + d * 64 + e];
    Wt[i] = (uint16_t)f32_bf16(acc);
  } else if (bid < PREP_W + PREP_X) {
    int i4 = (bid - PREP_W) * 256 + threadIdx.x;
    if (i4 >= (N_NODES + 1) * 16) return;
    ushort4 o;
    if (i4 < N_NODES * 16) {
      float4 f = ((const float4*)x)[i4];
      o.x = (uint16_t)f32_bf16(f.x);
      o.y = (uint16_t)f32_bf16(f.y);
      o.z = (uint16_t)f32_bf16(f.z);
      o.w = (uint16_t)f32_bf16(f.w);
    } else {
      o.x = 0; o.y = 0; o.z = 0; o.w = 0;
    }
    ((ushort4*)xb)[i4] = o;
  } else {
    int i = (bid - PREP_W - PREP_X) * 256 + threadIdx.x;
    if (i >= N_EDGES) return;
    int s = src[i], t = tgt[i], r = et[i];
    atomicAdd(&cnt[(t >> 7) * NREL + r], 1);
    atomicAdd(&cnt[(s >> 7) * NREL + r], 1);
  }
}

// exclusive scan of 16-aligned slot sizes; start[NKEY] = total
__global__ __launch_bounds__(256) void k_prefix(const int* __restrict__ cnt,
                                                int* __restrict__ start,
                                                int* __restrict__ cur) {
  __shared__ int ps[256];
  const int CH = (NKEY + 255) / 256;     // 98
  int t = threadIdx.x;
  int lo = t * CH;
  int hi = lo + CH; if (hi > NKEY) hi = NKEY;
  int s = 0;
  for (int i = lo; i < hi; ++i) s += (cnt[i] + 15) & ~15;
  ps[t] = s;
  __syncthreads();
  int incl = s;
  for (int off = 1; off < 256; off <<= 1) {
    int a = (t >= off) ? ps[t - off] : 0;
    __syncthreads();
    incl += a;
    ps[t] = incl;
    __syncthreads();
  }
  int run = incl - s;
  for (int i = lo; i < hi; ++i) {
    start[i] = run;
    cur[i] = run;
    run += (cnt[i] + 15) & ~15;
  }
  if (t == 255) start[NKEY] = run;
}

__global__ __launch_bounds__(256) void k_scat(const int* __restrict__ src,
                                              const int* __restrict__ tgt,
                                              const int* __restrict__ et,
                                              uint32_t* __restrict__ rec,
                                              int* __restrict__ cur, int nE) {
  int i = blockIdx.x * 256 + threadIdx.x;
  if (i >= nE) return;
  int s = src[i], t = tgt[i], r = et[i];
  int p1 = atomicAdd(&cur[(t >> 7) * NREL + r], 1);
  rec[p1] = ((uint32_t)(t & 127) << 23) | ((uint32_t)r << 18) | (uint32_t)s;
  int p2 = atomicAdd(&cur[(s >> 7) * NREL + r], 1);
  rec[p2] = ((uint32_t)(s & 127) << 23) | ((uint32_t)r << 18) | (uint32_t)t;
}

// one block per bucket; flattened tile list; native ds_add_f32 accumulation
__global__ __launch_bounds__(256, 4) void k_fused(const uint16_t* __restrict__ xb,
                                                  const uint32_t* __restrict__ recbuf,
                                                  const uint16_t* __restrict__ Wt,
                                                  const int* __restrict__ start,
                                                  const int* __restrict__ mask,
                                                  float* __restrict__ out) {
  __shared__ float lacc[ACCR * 68];      // stride 68; rows 128..135 = pad sinks
  const int b = blockIdx.x;
  const int base = b * BSZ;
  const int wid = threadIdx.x >> 6;
  const int lane = threadIdx.x & 63;
  const int quad = lane >> 4;
  const int m16 = lane & 15;

  {
    float4* z = (float4*)lacc;
    for (int i = threadIdx.x; i < ACCR * 68 / 4; i += 256)
      z[i] = make_float4(0.f, 0.f, 0.f, 0.f);
  }
  __syncthreads();

  const int bstart = start[b * NREL];
  const int bend = start[(b + 1) * NREL];
  const int ntiles = (bend - bstart) >> 4;

  int curRel = -1;
  short8b bf[4][2] = {};

  for (int t0 = wid * 8; t0 < ntiles; t0 += 32) {
    // ---- load 8 tiles of records: 2 coalesced loads ----
    int i0 = bstart + t0 * 16 + lane;
    int i1 = i0 + 64;
    uint32_t r0 = (i0 < bend) ? recbuf[i0] : 0xFFFFFFFFu;
    uint32_t r1 = (i1 < bend) ? recbuf[i1] : 0xFFFFFFFFu;

    // msg-aligned recs: lane holds msg m16's record for each tile
    uint32_t mrec[8];
#pragma unroll
    for (int it = 0; it < 4; ++it) mrec[it] = __shfl(r0, it * 16 + m16, 64);
#pragma unroll
    for (int it = 0; it < 4; ++it) mrec[4 + it] = __shfl(r1, it * 16 + m16, 64);

    // ---- gathers ----
    short8b a0[8], a1[8];
#pragma unroll
    for (int it = 0; it < 8; ++it) {
      uint32_t u = mrec[it] & 0x3FFFFu;
      if (u > N_NODES) u = N_NODES;      // sentinel -> zero row
      const uint16_t* xp = xb + (size_t)u * 64 + quad * 8;
      a0[it] = *(const short8b*)(xp);
      a1[it] = *(const short8b*)(xp + 32);
    }

    // ---- compute + LDS scatter per tile ----
#pragma unroll
    for (int it = 0; it < 8; ++it) {
      uint32_t tilerec = (it < 4) ? __shfl(r0, (it & 3) * 16, 64)
                                  : __shfl(r1, (it & 3) * 16, 64);
      int rel = (int)((tilerec >> 18) & 31);
      if (rel == 31) continue;           // tile fully past bucket end (uniform)
      if (rel != curRel) {
        curRel = rel;
        const uint16_t* wb = Wt + (size_t)rel * 4096;
#pragma unroll
        for (int nt = 0; nt < 4; ++nt)
#pragma unroll
          for (int kt = 0; kt < 2; ++kt)
            bf[nt][kt] = *(const short8b*)(wb + (size_t)(nt * 16 + m16) * 64 + kt * 32 + quad * 8);
      }
      float4v acc[4];
#pragma unroll
      for (int nt = 0; nt < 4; ++nt) { acc[nt][0] = 0.f; acc[nt][1] = 0.f; acc[nt][2] = 0.f; acc[nt][3] = 0.f; }
#pragma unroll
      for (int nt = 0; nt < 4; ++nt) {
        acc[nt] = __builtin_amdgcn_mfma_f32_16x16x32_bf16(a0[it], bf[nt][0], acc[nt], 0, 0, 0);
        acc[nt] = __builtin_amdgcn_mfma_f32_16x16x32_bf16(a1[it], bf[nt][1], acc[nt], 0, 0, 0);
      }
      // C/D: col = nt*16 + m16, row(msg) = quad*4 + reg
      int tl[4];
#pragma unroll
      for (int reg = 0; reg < 4; ++reg) {
        uint32_t sr = __shfl(mrec[it], quad * 4 + reg, 64);
        // pad-message sink rows 128..135 (receive only 0.0; de-hotspots ds unit)
        tl[reg] = (sr == 0xFFFFFFFFu) ? (BSZ + ((quad * 4 + reg) & 7))
                                      : (int)((sr >> 23) & 127);
      }
#pragma unroll
      for (int reg = 0; reg < 4; ++reg)
#pragma unroll
        for (int nt = 0; nt < 4; ++nt)
          unsafeAtomicAdd(&lacc[tl[reg] * 68 + nt * 16 + m16], acc[nt][reg]);
    }
  }

  // ---- self tiles (rel 16): wave wid handles node sub-tiles wid*2, wid*2+1 ----
  {
    const uint16_t* wb = Wt + (size_t)NREL * 4096;
    short8b bfs[4][2];
#pragma unroll
    for (int nt = 0; nt < 4; ++nt)
#pragma unroll
      for (int kt = 0; kt < 2; ++kt)
        bfs[nt][kt] = *(const short8b*)(wb + (size_t)(nt * 16 + m16) * 64 + kt * 32 + quad * 8);
#pragma unroll
    for (int j = 0; j < 2; ++j) {
      int s16 = wid * 2 + j;
      int node = base + s16 * 16 + m16;
      uint32_t u = (node < N_NODES && mask[node]) ? (uint32_t)node : (uint32_t)N_NODES;
      const uint16_t* xp = xb + (size_t)u * 64 + quad * 8;
      short8b a0 = *(const short8b*)(xp);
      short8b a1 = *(const short8b*)(xp + 32);
      float4v acc[4];
#pragma unroll
      for (int nt = 0; nt < 4; ++nt) { acc[nt][0] = 0.f; acc[nt][1] = 0.f; acc[nt][2] = 0.f; acc[nt][3] = 0.f; }
#pragma unroll
      for (int nt = 0; nt < 4; ++nt) {
        acc[nt] = __builtin_amdgcn_mfma_f32_16x16x32_bf16(a0, bfs[nt][0], acc[nt], 0, 0, 0);
        acc[nt] = __builtin_amdgcn_mfma_f32_16x16x32_bf16(a1, bfs[nt][1], acc[nt], 0, 0, 0);
      }
#pragma unroll
      for (int reg = 0; reg < 4; ++reg)
#pragma unroll
        for (int nt = 0; nt < 4; ++nt)
          unsafeAtomicAdd(&lacc[(s16 * 16 + quad * 4 + reg) * 68 + nt * 16 + m16], acc[nt][reg]);
    }
  }

  __syncthreads();
  // ---- writeout: 128 rows x 64 dims, float4/thread, coalesced ----
#pragma unroll
  for (int p = 0; p < 8; ++p) {
    int tloc = p * 16 + (threadIdx.x >> 4);
    int node = base + tloc;
    if (node < N_NODES) {
      int d = (threadIdx.x & 15) * 4;
      float4 v = *(const float4*)&lacc[tloc * 68 + d];
      *(float4*)(out + (size_t)node * 64 + d) = v;
    }
  }
}

extern "C" void kernel_launch(void* const* d_in, const int* in_sizes, int n_in,
                              void* d_out, int out_size, void* d_ws, size_t ws_size,
                              hipStream_t stream) {
  const float* x     = (const float*)d_in[0];
  const int*   mask  = (const int*)d_in[1];
  const int*   src   = (const int*)d_in[2];
  const int*   tgt   = (const int*)d_in[3];
  const int*   et    = (const int*)d_in[4];
  const float* bases = (const float*)d_in[5];
  const float* att   = (const float*)d_in[6];
  float* out = (float*)d_out;
  char* ws = (char*)d_ws;

  int*      cnt    = (int*)(ws + WS_CNT);
  int*      start  = (int*)(ws + WS_START);
  int*      cur    = (int*)(ws + WS_CUR);
  uint16_t* Wt     = (uint16_t*)(ws + WS_WT);
  uint16_t* xb     = (uint16_t*)(ws + WS_XB);
  uint32_t* recbuf = (uint32_t*)(ws + WS_REC);

  hipMemsetAsync(cnt, 0, NKEY * sizeof(int), stream);
  hipMemsetAsync(recbuf, 0xFF, (size_t)MAXREC * 4, stream);

  k_prep<<<PREP_W + PREP_X + PREP_C, 256, 0, stream>>>(bases, att, x, src, tgt, et, Wt, xb, cnt);
  k_prefix<<<1, 256, 0, stream>>>(cnt, start, cur);
  k_scat<<<(N_EDGES + 255) / 256, 256, 0, stream>>>(src, tgt, et, recbuf, cur, N_EDGES);
  k_fused<<<NB, 256, 0, stream>>>(xb, recbuf, Wt, start, mask, out);
}

// Round 6
// 898.120 us; speedup vs baseline: 1.2151x; 1.1981x over previous
//
#include <hip/hip_runtime.h>
#include <stdint.h>
#include <stddef.h>

#define N_NODES 200000
#define N_EDGES 800000
#define NREL 16
#define NBASES 8
#define BSZ 128
#define NB 1563                 // ceil(N_NODES/128)
#define NMSG (2 * N_EDGES)      // 1,600,000 edge messages (self handled by k_self)
#define T1B 1024
#define NBLK 782                // ceil(N_EDGES/1024)
#define BHP 1568                // padded bucket stride in bh
#define RCAP 1536               // recbuf slots per bucket (96 tiles)

// ---- workspace layout (bytes) ----
#define WS_WT   0               // 17*64*64 u16 = 139,264
#define WS_BH   139264          // NBLK*BHP int = 4,904,704 -> 5,043,968
#define WS_CT   5043968         // 1568 int (per-bucket totals)
#define WS_S    5050240         // 1568 int (bucket exclusive starts, S[NB]=total)
#define WS_TMP  5056512         // NMSG u32 = 6,400,000 -> 11,456,512
#define WS_TLOC 11456512        // NMSG u8 -> 13,056,512
#define WS_REC  13056512        // NB*RCAP int2 = 19,206,144 -> 32,262,656
#define WS_MSG  32262656        // NMSG * 64 u16 = 204,800,000 -> 237,062,656

typedef __attribute__((ext_vector_type(8))) short short8b;
typedef __attribute__((ext_vector_type(4))) float float4v;

__device__ __forceinline__ short f32_bf16(float f) {
  uint32_t u = __builtin_bit_cast(uint32_t, f);
  uint32_t r = u + 0x7FFFu + ((u >> 16) & 1u);
  return (short)(uint16_t)(r >> 16);
}
__device__ __forceinline__ float bf2f(uint32_t h) {
  return __builtin_bit_cast(float, h << 16);
}

// Wt[r][e][d] = bf16( sum_b att[r][b] * bases[b][d][e] )
__global__ __launch_bounds__(256) void k_wprep(const float* __restrict__ bases,
                                               const float* __restrict__ att,
                                               uint16_t* __restrict__ Wt) {
  int i = blockIdx.x * 256 + threadIdx.x;   // grid covers 17*4096 exactly
  int r = i >> 12, e = (i >> 6) & 63, d = i & 63;
  float acc = 0.f;
  for (int b = 0; b < NBASES; ++b)
    acc += att[r * NBASES + b] * bases[b * 4096 + d * 64 + e];
  Wt[i] = (uint16_t)f32_bf16(acc);
}

// T1: per-block LDS histogram over target buckets (both directions). No global atomics.
__global__ __launch_bounds__(T1B) void k_t1(const int* __restrict__ src,
                                            const int* __restrict__ tgt,
                                            int* __restrict__ bh) {
  __shared__ int h[NB];
  for (int i = threadIdx.x; i < NB; i += T1B) h[i] = 0;
  __syncthreads();
  int i = blockIdx.x * T1B + threadIdx.x;
  if (i < N_EDGES) {
    atomicAdd(&h[tgt[i] >> 7], 1);
    atomicAdd(&h[src[i] >> 7], 1);
  }
  __syncthreads();
  for (int i = threadIdx.x; i < NB; i += T1B)
    bh[blockIdx.x * BHP + i] = h[i];
}

// per-bucket column scan over blocks: bh[blk][b] -> exclusive prefix; ct[b]=total
__global__ __launch_bounds__(256) void k_scancol(int* __restrict__ bh,
                                                 int* __restrict__ ct) {
  __shared__ int col[NBLK];
  __shared__ int ps[256];
  int b = blockIdx.x;
  for (int i = threadIdx.x; i < NBLK; i += 256) col[i] = bh[i * BHP + b];
  __syncthreads();
  int lo = threadIdx.x * 4, hi = lo + 4;
  if (hi > NBLK) hi = NBLK;
  if (lo > NBLK) lo = NBLK;
  int s = 0;
  for (int i = lo; i < hi; ++i) s += col[i];
  ps[threadIdx.x] = s;
  __syncthreads();
  int incl = s;
  for (int off = 1; off < 256; off <<= 1) {
    int a = (threadIdx.x >= off) ? ps[threadIdx.x - off] : 0;
    __syncthreads();
    incl += a;
    ps[threadIdx.x] = incl;
    __syncthreads();
  }
  int run = incl - s;
  for (int i = lo; i < hi; ++i) { int c = col[i]; col[i] = run; run += c; }
  if (threadIdx.x == 0) ct[b] = ps[255];
  __syncthreads();
  for (int i = threadIdx.x; i < NBLK; i += 256) bh[i * BHP + b] = col[i];
}

// exclusive scan of bucket totals -> S[b]; S[NB] = grand total
__global__ __launch_bounds__(256) void k_scan1(const int* __restrict__ ct,
                                               int* __restrict__ S) {
  __shared__ int ps[256];
  int lo = threadIdx.x * 7, hi = lo + 7;
  if (hi > NB) hi = NB;
  if (lo > NB) lo = NB;
  int s = 0;
  for (int i = lo; i < hi; ++i) s += ct[i];
  ps[threadIdx.x] = s;
  __syncthreads();
  int incl = s;
  for (int off = 1; off < 256; off <<= 1) {
    int a = (threadIdx.x >= off) ? ps[threadIdx.x - off] : 0;
    __syncthreads();
    incl += a;
    ps[threadIdx.x] = incl;
    __syncthreads();
  }
  int run = incl - s;
  for (int i = lo; i < hi; ++i) { S[i] = run; run += ct[i]; }
  if (threadIdx.x == 255) S[NB] = run;
}

// T2: replay with LDS cursors (global-exact slots), write bucket-sorted tmp records.
// rec = node[0:18) | rel[18:23) | tloc[23:30)
__global__ __launch_bounds__(T1B) void k_t2(const int* __restrict__ src,
                                            const int* __restrict__ tgt,
                                            const int* __restrict__ et,
                                            const int* __restrict__ bh,
                                            const int* __restrict__ S,
                                            uint32_t* __restrict__ tmp) {
  __shared__ int cur[NB];
  for (int i = threadIdx.x; i < NB; i += T1B)
    cur[i] = S[i] + bh[blockIdx.x * BHP + i];
  __syncthreads();
  int i = blockIdx.x * T1B + threadIdx.x;
  if (i < N_EDGES) {
    int s = src[i], t = tgt[i];
    uint32_t r = (uint32_t)et[i];
    int p1 = atomicAdd(&cur[t >> 7], 1);
    tmp[p1] = (uint32_t)s | (r << 18) | ((uint32_t)(t & 127) << 23);
    int p2 = atomicAdd(&cur[s >> 7], 1);
    tmp[p2] = (uint32_t)t | (r << 18) | ((uint32_t)(s & 127) << 23);
  }
}

// T3: per-bucket rel-sort in LDS; emit padded rel-uniform tiles + exact msg slots.
__global__ __launch_bounds__(256) void k_t3(const uint32_t* __restrict__ tmp,
                                            const int* __restrict__ S,
                                            int2* __restrict__ recbuf,
                                            uint8_t* __restrict__ tlocArr) {
  __shared__ uint32_t rr[1600];
  __shared__ int h[NREL], pad[NREL], ex[NREL], cu[NREL];
  int b = blockIdx.x;
  int s0 = S[b];
  int n = S[b + 1] - s0;
  if (n > 1600) n = 1600;
  if (threadIdx.x < NREL) h[threadIdx.x] = 0;
  __syncthreads();
  for (int i = threadIdx.x; i < n; i += 256) {
    uint32_t v = tmp[s0 + i];
    rr[i] = v;
    atomicAdd(&h[(v >> 18) & 31], 1);
  }
  __syncthreads();
  if (threadIdx.x == 0) {
    int rp = 0, re = 0;
    for (int r = 0; r < NREL; ++r) {
      pad[r] = rp; ex[r] = re; cu[r] = 0;
      rp += (h[r] + 15) & ~15;
      re += h[r];
    }
  }
  __syncthreads();
  for (int i = threadIdx.x; i < n; i += 256) {
    uint32_t v = rr[i];
    int r = (v >> 18) & 31;
    int j = atomicAdd(&cu[r], 1);
    int slot = s0 + ex[r] + j;
    recbuf[b * RCAP + pad[r] + j] = make_int2((int)(v & 0x7FFFFF), slot);
    tlocArr[slot] = (uint8_t)(v >> 23);
  }
}

// phaseA: wave = 4 rel-uniform tiles; gather x(fp32)->bf16, MFMA, LDS transpose,
// contiguous bf16 row stores at exact target-sorted slots. No barriers, no atomics.
__global__ __launch_bounds__(256) void k_phaseA(const float* __restrict__ x,
                                               const int2* __restrict__ recbuf,
                                               const uint16_t* __restrict__ Wt,
                                               uint16_t* __restrict__ msg) {
  __shared__ uint16_t s_m[4][16 * 72];
  __shared__ int s_slot[4][16];
  const int b = blockIdx.x / 6;
  const int g = blockIdx.x % 6;
  const int wid = threadIdx.x >> 6;
  const int lane = threadIdx.x & 63;
  const int quad = lane >> 4;
  const int m16 = lane & 15;

  const int2* tb = recbuf + (size_t)b * RCAP + (g * 4 + wid) * 64;
  int2 rec = tb[lane];                    // 64 records = 4 tiles

  int curRel = -1;
  short8b bf[4][2] = {};

  for (int it = 0; it < 4; ++it) {
    int relx = __shfl(rec.x, it * 16, 64);
    if (relx == -1) continue;             // tile fully padded (wave-uniform)
    int rel = (relx >> 18) & 31;
    if (rel != curRel) {
      curRel = rel;
      const uint16_t* wb = Wt + (size_t)rel * 4096;
#pragma unroll
      for (int nt = 0; nt < 4; ++nt)
#pragma unroll
        for (int kt = 0; kt < 2; ++kt)
          bf[nt][kt] = *(const short8b*)(wb + (size_t)(nt * 16 + m16) * 64 + kt * 32 + quad * 8);
    }
    int mx = __shfl(rec.x, it * 16 + m16, 64);
    int my = __shfl(rec.y, it * 16 + m16, 64);
    uint32_t u = (uint32_t)mx & 0x3FFFFu;
    if (u >= N_NODES) u = 0;              // pad record: garbage row, store skipped

    const float* xp = x + (size_t)u * 64 + quad * 8;
    float4v q0 = *(const float4v*)(xp);
    float4v q1 = *(const float4v*)(xp + 4);
    float4v q2 = *(const float4v*)(xp + 32);
    float4v q3 = *(const float4v*)(xp + 36);
    short8b a0, a1;
    a0[0] = f32_bf16(q0[0]); a0[1] = f32_bf16(q0[1]); a0[2] = f32_bf16(q0[2]); a0[3] = f32_bf16(q0[3]);
    a0[4] = f32_bf16(q1[0]); a0[5] = f32_bf16(q1[1]); a0[6] = f32_bf16(q1[2]); a0[7] = f32_bf16(q1[3]);
    a1[0] = f32_bf16(q2[0]); a1[1] = f32_bf16(q2[1]); a1[2] = f32_bf16(q2[2]); a1[3] = f32_bf16(q2[3]);
    a1[4] = f32_bf16(q3[0]); a1[5] = f32_bf16(q3[1]); a1[6] = f32_bf16(q3[2]); a1[7] = f32_bf16(q3[3]);

    float4v acc[4];
#pragma unroll
    for (int nt = 0; nt < 4; ++nt) { acc[nt][0] = 0.f; acc[nt][1] = 0.f; acc[nt][2] = 0.f; acc[nt][3] = 0.f; }
#pragma unroll
    for (int nt = 0; nt < 4; ++nt) {
      acc[nt] = __builtin_amdgcn_mfma_f32_16x16x32_bf16(a0, bf[nt][0], acc[nt], 0, 0, 0);
      acc[nt] = __builtin_amdgcn_mfma_f32_16x16x32_bf16(a1, bf[nt][1], acc[nt], 0, 0, 0);
    }

    // C/D: col(dim)=nt*16+m16, row(msg)=quad*4+reg -> transpose via per-wave LDS
    if (quad == 0) s_slot[wid][m16] = my;
#pragma unroll
    for (int reg = 0; reg < 4; ++reg)
#pragma unroll
      for (int nt = 0; nt < 4; ++nt)
        s_m[wid][(quad * 4 + reg) * 72 + nt * 16 + m16] = (uint16_t)f32_bf16(acc[nt][reg]);

    // 16 rows x 128 B; 8 lanes/row x 16 B; rows in a tile go to consecutive slots
#pragma unroll
    for (int p = 0; p < 2; ++p) {
      int row = (lane >> 3) + p * 8;
      int slot = s_slot[wid][row];
      if (slot >= 0) {
        int4 val = *(const int4*)&s_m[wid][row * 72 + (lane & 7) * 8];
        *(int4*)(msg + (size_t)slot * 64 + (lane & 7) * 8) = val;
      }
    }
  }
}

// phaseB: per-bucket streaming segmented sum into LDS (ds_add), fp32 writeout.
__global__ __launch_bounds__(256) void k_phaseB(const uint16_t* __restrict__ msg,
                                                const uint8_t* __restrict__ tlocArr,
                                                const int* __restrict__ S,
                                                float* __restrict__ out) {
  __shared__ float lacc[BSZ * 68];
  int b = blockIdx.x;
  {
    float4* z = (float4*)lacc;
    for (int i = threadIdx.x; i < BSZ * 68 / 4; i += 256)
      z[i] = make_float4(0.f, 0.f, 0.f, 0.f);
  }
  __syncthreads();
  int s0 = S[b];
  int n = S[b + 1] - s0;
  int row8 = threadIdx.x >> 5;            // 8 rows per iteration
  int dp = threadIdx.x & 31;              // dim pair
  for (int base = 0; base < n; base += 8) {
    int ri = base + row8;
    if (ri < n) {
      int g = s0 + ri;
      uint32_t hh = *(const uint32_t*)(msg + (size_t)g * 64 + dp * 2);
      int tl = tlocArr[g];
      unsafeAtomicAdd(&lacc[tl * 68 + dp * 2], bf2f(hh & 0xFFFFu));
      unsafeAtomicAdd(&lacc[tl * 68 + dp * 2 + 1], bf2f(hh >> 16));
    }
  }
  __syncthreads();
#pragma unroll
  for (int p = 0; p < 8; ++p) {
    int tloc = p * 16 + (threadIdx.x >> 4);
    int node = b * BSZ + tloc;
    if (node < N_NODES) {
      int d = (threadIdx.x & 15) * 4;
      float4 v = *(const float4*)&lacc[tloc * 68 + d];
      *(float4*)(out + (size_t)node * 64 + d) = v;
    }
  }
}

// k_self: out += mask * (x @ W16), one 16-node tile per wave, MFMA with C=out.
__global__ __launch_bounds__(256) void k_self(const float* __restrict__ x,
                                              const int* __restrict__ mask,
                                              const uint16_t* __restrict__ Wt,
                                              float* __restrict__ out) {
  __shared__ float st[4][16 * 64];
  const int wid = threadIdx.x >> 6;
  const int lane = threadIdx.x & 63;
  const int quad = lane >> 4;
  const int m16 = lane & 15;
  const int tile = blockIdx.x * 4 + wid;  // 12500 tiles cover 200000 exactly
  float* op = out + (size_t)tile * 16 * 64;

  // load out tile coalesced -> LDS
  float4* stv = (float4*)st[wid];
#pragma unroll
  for (int k = 0; k < 4; ++k)
    stv[lane + k * 64] = ((const float4*)op)[lane + k * 64];

  // C fragments
  float4v acc[4];
#pragma unroll
  for (int nt = 0; nt < 4; ++nt)
#pragma unroll
    for (int reg = 0; reg < 4; ++reg)
      acc[nt][reg] = st[wid][(quad * 4 + reg) * 64 + nt * 16 + m16];

  // A: x row (mask-gated)
  int node = tile * 16 + m16;
  int mk = mask[node];
  const float* xp = x + (size_t)node * 64 + quad * 8;
  float4v q0 = *(const float4v*)(xp);
  float4v q1 = *(const float4v*)(xp + 4);
  float4v q2 = *(const float4v*)(xp + 32);
  float4v q3 = *(const float4v*)(xp + 36);
  short8b a0, a1;
  if (mk) {
    a0[0] = f32_bf16(q0[0]); a0[1] = f32_bf16(q0[1]); a0[2] = f32_bf16(q0[2]); a0[3] = f32_bf16(q0[3]);
    a0[4] = f32_bf16(q1[0]); a0[5] = f32_bf16(q1[1]); a0[6] = f32_bf16(q1[2]); a0[7] = f32_bf16(q1[3]);
    a1[0] = f32_bf16(q2[0]); a1[1] = f32_bf16(q2[1]); a1[2] = f32_bf16(q2[2]); a1[3] = f32_bf16(q2[3]);
    a1[4] = f32_bf16(q3[0]); a1[5] = f32_bf16(q3[1]); a1[6] = f32_bf16(q3[2]); a1[7] = f32_bf16(q3[3]);
  } else {
#pragma unroll
    for (int j = 0; j < 8; ++j) { a0[j] = 0; a1[j] = 0; }
  }

  const uint16_t* wb = Wt + (size_t)NREL * 4096;
#pragma unroll
  for (int nt = 0; nt < 4; ++nt) {
    short8b b0 = *(const short8b*)(wb + (size_t)(nt * 16 + m16) * 64 + quad * 8);
    short8b b1 = *(const short8b*)(wb + (size_t)(nt * 16 + m16) * 64 + 32 + quad * 8);
    acc[nt] = __builtin_amdgcn_mfma_f32_16x16x32_bf16(a0, b0, acc[nt], 0, 0, 0);
    acc[nt] = __builtin_amdgcn_mfma_f32_16x16x32_bf16(a1, b1, acc[nt], 0, 0, 0);
  }

  // D -> LDS -> coalesced store
#pragma unroll
  for (int nt = 0; nt < 4; ++nt)
#pragma unroll
    for (int reg = 0; reg < 4; ++reg)
      st[wid][(quad * 4 + reg) * 64 + nt * 16 + m16] = acc[nt][reg];
#pragma unroll
  for (int k = 0; k < 4; ++k)
    ((float4*)op)[lane + k * 64] = stv[lane + k * 64];
}

extern "C" void kernel_launch(void* const* d_in, const int* in_sizes, int n_in,
                              void* d_out, int out_size, void* d_ws, size_t ws_size,
                              hipStream_t stream) {
  const float* x     = (const float*)d_in[0];
  const int*   mask  = (const int*)d_in[1];
  const int*   src   = (const int*)d_in[2];
  const int*   tgt   = (const int*)d_in[3];
  const int*   et    = (const int*)d_in[4];
  const float* bases = (const float*)d_in[5];
  const float* att   = (const float*)d_in[6];
  float* out = (float*)d_out;
  char* ws = (char*)d_ws;

  uint16_t* Wt      = (uint16_t*)(ws + WS_WT);
  int*      bh      = (int*)(ws + WS_BH);
  int*      ct      = (int*)(ws + WS_CT);
  int*      S       = (int*)(ws + WS_S);
  uint32_t* tmp     = (uint32_t*)(ws + WS_TMP);
  uint8_t*  tlocArr = (uint8_t*)(ws + WS_TLOC);
  int2*     recbuf  = (int2*)(ws + WS_REC);
  uint16_t* msg     = (uint16_t*)(ws + WS_MSG);

  hipMemsetAsync(bh, 0, (size_t)NBLK * BHP * 4, stream);
  hipMemsetAsync(recbuf, 0xFF, (size_t)NB * RCAP * 8, stream);

  k_wprep<<<272, 256, 0, stream>>>(bases, att, Wt);
  k_t1<<<NBLK, T1B, 0, stream>>>(src, tgt, bh);
  k_scancol<<<NB, 256, 0, stream>>>(bh, ct);
  k_scan1<<<1, 256, 0, stream>>>(ct, S);
  k_t2<<<NBLK, T1B, 0, stream>>>(src, tgt, et, bh, S, tmp);
  k_t3<<<NB, 256, 0, stream>>>(tmp, S, recbuf, tlocArr);
  k_phaseA<<<NB * 6, 256, 0, stream>>>(x, recbuf, Wt, msg);
  k_phaseB<<<NB, 256, 0, stream>>>(msg, tlocArr, S, out);
  k_self<<<3125, 256, 0, stream>>>(x, mask, Wt, out);
}